// Round 1
// baseline (914.691 us; speedup 1.0000x reference)
//
#include <hip/hip_runtime.h>
#include <cstdint>
#include <cstddef>

typedef __bf16 bf16_t;
typedef bf16_t bf16x8 __attribute__((ext_vector_type(8)));
typedef bf16_t bf16x4 __attribute__((ext_vector_type(4)));
typedef float  floatx4 __attribute__((ext_vector_type(4)));

#define S_LEN 2048
#define DIM_  4096
#define NH    32
#define NKV   8
#define HD    128
#define KV_DIM (NKV * HD)   // 1024

// ---------------------------------------------------------------------------
// elementwise fp32 -> bf16 (n divisible by 4)
// ---------------------------------------------------------------------------
__global__ void f32_to_bf16_kernel(const float* __restrict__ in,
                                   bf16_t* __restrict__ out, int n) {
    int i = (blockIdx.x * blockDim.x + threadIdx.x) * 4;
    if (i >= n) return;
    float4 v = *(const float4*)(in + i);
    bf16x4 o;
    o[0] = (bf16_t)v.x; o[1] = (bf16_t)v.y; o[2] = (bf16_t)v.z; o[3] = (bf16_t)v.w;
    *(bf16x4*)(out + i) = o;
}

// ---------------------------------------------------------------------------
// transpose-convert: in [R][C] (fp32 or bf16) -> out [C][R] bf16
// block (32,8), grid (C/32, R/32)
// ---------------------------------------------------------------------------
template <typename InT>
__global__ void transpose_to_bf16_kernel(const InT* __restrict__ in,
                                         bf16_t* __restrict__ out, int R, int C) {
    __shared__ float tile[32][33];
    int bx = blockIdx.x * 32;   // C offset
    int by = blockIdx.y * 32;   // R offset
    int tx = threadIdx.x, ty = threadIdx.y;
#pragma unroll
    for (int i = 0; i < 4; i++) {
        int r = ty + i * 8;
        tile[r][tx] = (float)in[(size_t)(by + r) * C + bx + tx];
    }
    __syncthreads();
#pragma unroll
    for (int i = 0; i < 4; i++) {
        int r = ty + i * 8;  // local C index
        out[(size_t)(bx + r) * R + by + tx] = (bf16_t)tile[tx][r];
    }
}

// ---------------------------------------------------------------------------
// bf16 GEMM:  C[M][N] = A[M][K] @ B^T   with BT stored [N][K] row-major.
// 128x128 tile, BK=32, 256 threads = 4 waves in 2x2, each wave 64x64 via
// 4x4 mfma_f32_16x16x32_bf16.  fp32 accumulate, OutT output.
// ---------------------------------------------------------------------------
template <typename OutT>
__global__ __launch_bounds__(256) void gemm_bt_kernel(
        const bf16_t* __restrict__ A,   // [M][K]
        const bf16_t* __restrict__ BT,  // [N][K]
        OutT* __restrict__ C,           // [M][N]
        int M, int N, int K) {
    constexpr int BM = 128, BN = 128, BK = 32, PAD = 8;
    __shared__ bf16_t As[BM][BK + PAD];
    __shared__ bf16_t Bs[BN][BK + PAD];

    const int tid  = threadIdx.x;
    const int lane = tid & 63;
    const int wave = tid >> 6;
    const int wm = (wave >> 1) * 64;
    const int wn = (wave & 1) * 64;
    const int quad = lane >> 4;
    const int l16  = lane & 15;
    const int m0 = blockIdx.y * BM;
    const int n0 = blockIdx.x * BN;

    const int sr = tid >> 2;          // 0..63 staging row
    const int sc = (tid & 3) * 8;     // staging col group

    floatx4 acc[4][4] = {};

    for (int k0 = 0; k0 < K; k0 += BK) {
        const bf16_t* Ag = A  + (size_t)(m0 + sr) * K + k0 + sc;
        const bf16_t* Bg = BT + (size_t)(n0 + sr) * K + k0 + sc;
        *(bf16x8*)&As[sr][sc]      = *(const bf16x8*)Ag;
        *(bf16x8*)&As[sr + 64][sc] = *(const bf16x8*)(Ag + (size_t)64 * K);
        *(bf16x8*)&Bs[sr][sc]      = *(const bf16x8*)Bg;
        *(bf16x8*)&Bs[sr + 64][sc] = *(const bf16x8*)(Bg + (size_t)64 * K);
        __syncthreads();

        bf16x8 af[4], bf[4];
#pragma unroll
        for (int mt = 0; mt < 4; mt++)
            af[mt] = *(const bf16x8*)&As[wm + mt * 16 + l16][quad * 8];
#pragma unroll
        for (int nt = 0; nt < 4; nt++)
            bf[nt] = *(const bf16x8*)&Bs[wn + nt * 16 + l16][quad * 8];
#pragma unroll
        for (int mt = 0; mt < 4; mt++)
#pragma unroll
            for (int nt = 0; nt < 4; nt++)
                acc[mt][nt] = __builtin_amdgcn_mfma_f32_16x16x32_bf16(
                    af[mt], bf[nt], acc[mt][nt], 0, 0, 0);
        __syncthreads();
    }

#pragma unroll
    for (int mt = 0; mt < 4; mt++)
#pragma unroll
        for (int nt = 0; nt < 4; nt++)
#pragma unroll
            for (int rg = 0; rg < 4; rg++) {
                int row = m0 + wm + mt * 16 + quad * 4 + rg;
                int col = n0 + wn + nt * 16 + l16;
                C[(size_t)row * N + col] = (OutT)acc[mt][nt][rg];
            }
}

// ---------------------------------------------------------------------------
// RoPE in-place on bf16 [S][nheads*HD], interleaved pairs (2i, 2i+1).
// one thread per (s, head, freq-pair)
// ---------------------------------------------------------------------------
__global__ void rope_kernel(bf16_t* __restrict__ t,
                            const float* __restrict__ cosb,
                            const float* __restrict__ sinb, int nheads) {
    int idx = blockIdx.x * blockDim.x + threadIdx.x;  // S*nheads*64
    int i = idx & 63;
    int rest = idx >> 6;
    int hh = rest % nheads;
    int s  = rest / nheads;
    float c  = cosb[s * 64 + i];
    float sn = sinb[s * 64 + i];
    size_t base = (size_t)s * nheads * HD + (size_t)hh * HD + 2 * i;
    float re = (float)t[base], im = (float)t[base + 1];
    t[base]     = (bf16_t)(re * c - im * sn);
    t[base + 1] = (bf16_t)(re * sn + im * c);
}

// ---------------------------------------------------------------------------
// Flash attention (causal), bf16 in/out.
//  Qb  [S][NH*HD]  (roped)
//  Kb  [S][NKV*HD] (roped)
//  Vt  [NKV][HD][S]  (V transposed)
//  O   [S][NH*HD]
// block: 256 thr = 4 waves, 64 q-rows per block (16 per wave), k-tiles of 64.
// ---------------------------------------------------------------------------
__global__ __launch_bounds__(256) void attn_kernel(
        const bf16_t* __restrict__ Qb, const bf16_t* __restrict__ Kb,
        const bf16_t* __restrict__ Vt, bf16_t* __restrict__ O) {
    constexpr int BQ = 64, BK = 64;
    __shared__ bf16_t Ks[BK][HD];           // 16 KB
    __shared__ bf16_t Vs[HD][BK];           // 16 KB
    __shared__ bf16_t Ps[4][16][BK + 8];    // 9 KB, wave-private rows

    const int tid  = threadIdx.x;
    const int lane = tid & 63;
    const int wave = tid >> 6;
    const int quad = lane >> 4;
    const int l16  = lane & 15;
    const int h    = blockIdx.y;
    const int hkv  = h >> 2;               // N_REP = 4
    const int q0   = blockIdx.x * BQ;

    // Q fragments (A-operand layout: m = l16, k = chunk*32 + quad*8 + j)
    bf16x8 qf[4];
    {
        const bf16_t* Qg = Qb + (size_t)(q0 + wave * 16 + l16) * (NH * HD) + (size_t)h * HD;
#pragma unroll
        for (int c = 0; c < 4; c++)
            qf[c] = *(const bf16x8*)(Qg + c * 32 + quad * 8);
    }

    floatx4 o_acc[8] = {};
    float m_run[4], l_run[4];
#pragma unroll
    for (int i = 0; i < 4; i++) { m_run[i] = -1e30f; l_run[i] = 0.f; }
    const float scale = 0.08838834764831845f;  // 1/sqrt(128)

    const int ntiles = q0 / BK + 1;
    for (int t = 0; t < ntiles; t++) {
        const int k0 = t * BK;
        // stage K tile [64][128]
        {
            int rr = tid >> 4;            // 0..15
            int cc = (tid & 15) * 8;      // 0..120
#pragma unroll
            for (int p = 0; p < 4; p++)
                *(bf16x8*)&Ks[p * 16 + rr][cc] =
                    *(const bf16x8*)(Kb + (size_t)(k0 + p * 16 + rr) * KV_DIM + (size_t)hkv * HD + cc);
            // stage V^T tile [128][64]
            int vr = tid >> 3;            // 0..31
            int vc = (tid & 7) * 8;       // 0..56
            const bf16_t* Vg = Vt + (size_t)hkv * HD * S_LEN + k0;
#pragma unroll
            for (int p = 0; p < 4; p++)
                *(bf16x8*)&Vs[p * 32 + vr][vc] =
                    *(const bf16x8*)(Vg + (size_t)(p * 32 + vr) * S_LEN + vc);
        }
        __syncthreads();

        // S = Q K^T  (16 x 64 per wave)
        floatx4 sc[4] = {};
#pragma unroll
        for (int nt = 0; nt < 4; nt++)
#pragma unroll
            for (int ks = 0; ks < 4; ks++) {
                bf16x8 kf = *(const bf16x8*)&Ks[nt * 16 + l16][ks * 32 + quad * 8];
                sc[nt] = __builtin_amdgcn_mfma_f32_16x16x32_bf16(qf[ks], kf, sc[nt], 0, 0, 0);
            }

        const bool diag = (k0 == q0);
#pragma unroll
        for (int nt = 0; nt < 4; nt++)
#pragma unroll
            for (int rg = 0; rg < 4; rg++) {
                float s = sc[nt][rg] * scale;
                if (diag) {
                    int qg = wave * 16 + quad * 4 + rg;
                    int kg = nt * 16 + l16;
                    if (kg > qg) s = -1e30f;
                }
                sc[nt][rg] = s;
            }

        // online softmax (row = quad*4+rg; cols across l16 and nt)
        float alpha[4];
#pragma unroll
        for (int rg = 0; rg < 4; rg++) {
            float m = fmaxf(fmaxf(sc[0][rg], sc[1][rg]), fmaxf(sc[2][rg], sc[3][rg]));
#pragma unroll
            for (int off = 8; off >= 1; off >>= 1)
                m = fmaxf(m, __shfl_xor(m, off, 64));
            float mn = fmaxf(m_run[rg], m);
            alpha[rg] = __expf(m_run[rg] - mn);
            m_run[rg] = mn;
        }
        float rsum[4] = {0.f, 0.f, 0.f, 0.f};
#pragma unroll
        for (int nt = 0; nt < 4; nt++)
#pragma unroll
            for (int rg = 0; rg < 4; rg++) {
                float p = __expf(sc[nt][rg] - m_run[rg]);
                sc[nt][rg] = p;
                rsum[rg] += p;
            }
#pragma unroll
        for (int rg = 0; rg < 4; rg++) {
            float s = rsum[rg];
#pragma unroll
            for (int off = 8; off >= 1; off >>= 1)
                s += __shfl_xor(s, off, 64);
            l_run[rg] = l_run[rg] * alpha[rg] + s;
        }
#pragma unroll
        for (int dt = 0; dt < 8; dt++)
#pragma unroll
            for (int rg = 0; rg < 4; rg++) o_acc[dt][rg] *= alpha[rg];

        // P (C-layout) -> LDS -> A-layout, wave-private so no barrier
#pragma unroll
        for (int nt = 0; nt < 4; nt++)
#pragma unroll
            for (int rg = 0; rg < 4; rg++)
                Ps[wave][quad * 4 + rg][nt * 16 + l16] = (bf16_t)sc[nt][rg];
        asm volatile("s_waitcnt lgkmcnt(0)" ::: "memory");

        // O += P V
#pragma unroll
        for (int ks = 0; ks < 2; ks++) {
            bf16x8 pf = *(const bf16x8*)&Ps[wave][l16][ks * 32 + quad * 8];
#pragma unroll
            for (int dt = 0; dt < 8; dt++) {
                bf16x8 vf = *(const bf16x8*)&Vs[dt * 16 + l16][ks * 32 + quad * 8];
                o_acc[dt] = __builtin_amdgcn_mfma_f32_16x16x32_bf16(pf, vf, o_acc[dt], 0, 0, 0);
            }
        }
        __syncthreads();
    }

    // epilogue
#pragma unroll
    for (int rg = 0; rg < 4; rg++) {
        float inv_l = 1.0f / l_run[rg];
#pragma unroll
        for (int dt = 0; dt < 8; dt++) {
            int row = q0 + wave * 16 + quad * 4 + rg;
            int col = h * HD + dt * 16 + l16;
            O[(size_t)row * (NH * HD) + col] = (bf16_t)(o_acc[dt][rg] * inv_l);
        }
    }
}

// ---------------------------------------------------------------------------
// launch
// ---------------------------------------------------------------------------
extern "C" void kernel_launch(void* const* d_in, const int* in_sizes, int n_in,
                              void* d_out, int out_size, void* d_ws, size_t ws_size,
                              hipStream_t stream) {
    const float* x    = (const float*)d_in[0];
    const float* wq   = (const float*)d_in[1];
    const float* wk   = (const float*)d_in[2];
    const float* wv   = (const float*)d_in[3];
    const float* wo   = (const float*)d_in[4];
    const float* fcos = (const float*)d_in[5];
    const float* fsin = (const float*)d_in[6];
    float* out = (float*)d_out;

    char* ws = (char*)d_ws;
    constexpr size_t MB = 1024 * 1024;
    bf16_t* xb    = (bf16_t*)(ws + 0 * MB);     // 16 MB  [2048][4096]
    bf16_t* wqT   = (bf16_t*)(ws + 16 * MB);    // 32 MB  [4096][4096]
    bf16_t* wkT   = (bf16_t*)(ws + 48 * MB);    //  8 MB  [1024][4096]
    bf16_t* wvT   = (bf16_t*)(ws + 56 * MB);    //  8 MB  [1024][4096]
    bf16_t* woT   = (bf16_t*)(ws + 64 * MB);    // 32 MB  [4096][4096]
    bf16_t* Qb    = (bf16_t*)(ws + 96 * MB);    // 16 MB  [2048][4096]
    bf16_t* Kb    = (bf16_t*)(ws + 112 * MB);   //  4 MB  [2048][1024]
    bf16_t* Vb0   = (bf16_t*)(ws + 116 * MB);   //  4 MB  [2048][1024]
    bf16_t* Vt    = (bf16_t*)(ws + 120 * MB);   //  4 MB  [8][128][2048]
    bf16_t* attnb = (bf16_t*)(ws + 124 * MB);   // 16 MB  [2048][4096]

    dim3 tb32(32, 8);

    // 1. convert / transpose-convert
    f32_to_bf16_kernel<<<(S_LEN * DIM_ / 4) / 256, 256, 0, stream>>>(x, xb, S_LEN * DIM_);
    transpose_to_bf16_kernel<float><<<dim3(DIM_ / 32, DIM_ / 32), tb32, 0, stream>>>(wq, wqT, DIM_, DIM_);
    transpose_to_bf16_kernel<float><<<dim3(KV_DIM / 32, DIM_ / 32), tb32, 0, stream>>>(wk, wkT, DIM_, KV_DIM);
    transpose_to_bf16_kernel<float><<<dim3(KV_DIM / 32, DIM_ / 32), tb32, 0, stream>>>(wv, wvT, DIM_, KV_DIM);
    transpose_to_bf16_kernel<float><<<dim3(DIM_ / 32, DIM_ / 32), tb32, 0, stream>>>(wo, woT, DIM_, DIM_);

    // 2. QKV projections (bf16 out)
    gemm_bt_kernel<bf16_t><<<dim3(DIM_ / 128, S_LEN / 128), 256, 0, stream>>>(xb, wqT, Qb, S_LEN, DIM_, DIM_);
    gemm_bt_kernel<bf16_t><<<dim3(KV_DIM / 128, S_LEN / 128), 256, 0, stream>>>(xb, wkT, Kb, S_LEN, KV_DIM, DIM_);
    gemm_bt_kernel<bf16_t><<<dim3(KV_DIM / 128, S_LEN / 128), 256, 0, stream>>>(xb, wvT, Vb0, S_LEN, KV_DIM, DIM_);

    // 3. RoPE (in-place) + V transpose
    rope_kernel<<<(S_LEN * NH * 64) / 256, 256, 0, stream>>>(Qb, fcos, fsin, NH);
    rope_kernel<<<(S_LEN * NKV * 64) / 256, 256, 0, stream>>>(Kb, fcos, fsin, NKV);
    transpose_to_bf16_kernel<bf16_t><<<dim3(KV_DIM / 32, S_LEN / 32), tb32, 0, stream>>>(Vb0, Vt, S_LEN, KV_DIM);

    // 4. causal flash attention
    attn_kernel<<<dim3(S_LEN / 64, NH), 256, 0, stream>>>(Qb, Kb, Vt, attnb);

    // 5. output projection (fp32 out)
    gemm_bt_kernel<float><<<dim3(DIM_ / 128, S_LEN / 128), 256, 0, stream>>>(attnb, woT, out, S_LEN, DIM_, DIM_);
}

// Round 2
// 606.480 us; speedup vs baseline: 1.5082x; 1.5082x over previous
//
#include <hip/hip_runtime.h>
#include <cstdint>
#include <cstddef>

typedef __bf16 bf16_t;
typedef bf16_t bf16x8 __attribute__((ext_vector_type(8)));
typedef float  floatx4 __attribute__((ext_vector_type(4)));

#define S_LEN 2048
#define DIM_  4096
#define NH    32
#define NKV   8
#define HD    128
#define KV_DIM (NKV * HD)        // 1024
#define QLD   (DIM_ + 2 * KV_DIM) // 6144: fused QKV row stride

// async global->LDS, 16B per lane (lane-contiguous LDS dest required)
__device__ __forceinline__ void gload_lds16(const bf16_t* g, bf16_t* l) {
    __builtin_amdgcn_global_load_lds(
        (const __attribute__((address_space(1))) void*)g,
        (__attribute__((address_space(3))) void*)l, 16, 0, 0);
}

// ---------------------------------------------------------------------------
// fp32 -> bf16, 8 elements / thread
// ---------------------------------------------------------------------------
__global__ void f32_to_bf16_kernel(const float* __restrict__ in,
                                   bf16_t* __restrict__ out, int n) {
    int i = (blockIdx.x * blockDim.x + threadIdx.x) * 8;
    if (i >= n) return;
    float4 a = *(const float4*)(in + i);
    float4 b = *(const float4*)(in + i + 4);
    bf16x8 o;
    o[0] = (bf16_t)a.x; o[1] = (bf16_t)a.y; o[2] = (bf16_t)a.z; o[3] = (bf16_t)a.w;
    o[4] = (bf16_t)b.x; o[5] = (bf16_t)b.y; o[6] = (bf16_t)b.z; o[7] = (bf16_t)b.w;
    *(bf16x8*)(out + i) = o;
}

// ---------------------------------------------------------------------------
// all 4 weight transposes in ONE kernel.
// wq[4096][4096]->wqkvT rows 0..4095 ; wk[4096][1024]->rows 4096..5119 ;
// wv[4096][1024]->rows 5120..6143 ; wo[4096][4096]->woT.  out row stride 4096.
// block (32,8), 1-D grid of 40960 blocks.
// ---------------------------------------------------------------------------
__global__ void transpose_weights_kernel(const float* __restrict__ wq,
                                         const float* __restrict__ wk,
                                         const float* __restrict__ wv,
                                         const float* __restrict__ wo,
                                         bf16_t* __restrict__ wqkvT,
                                         bf16_t* __restrict__ woT) {
    __shared__ float tile[32][33];
    int bid = blockIdx.x;
    const float* in; bf16_t* out; int C;
    if (bid < 16384)      { in = wq; out = wqkvT;                          C = 4096; }
    else if (bid < 20480) { bid -= 16384; in = wk; out = wqkvT + (size_t)4096 * 4096; C = 1024; }
    else if (bid < 24576) { bid -= 20480; in = wv; out = wqkvT + (size_t)5120 * 4096; C = 1024; }
    else                  { bid -= 24576; in = wo; out = woT;              C = 4096; }
    int gpr = C / 32;
    int bx = (bid % gpr) * 32;   // col offset in input
    int by = (bid / gpr) * 32;   // row offset in input (K dim, 4096)
    int tx = threadIdx.x, ty = threadIdx.y;
#pragma unroll
    for (int i = 0; i < 4; i++) {
        int r = ty + i * 8;
        tile[r][tx] = in[(size_t)(by + r) * C + bx + tx];
    }
    __syncthreads();
#pragma unroll
    for (int i = 0; i < 4; i++) {
        int r = ty + i * 8;
        out[(size_t)(bx + r) * 4096 + by + tx] = (bf16_t)tile[tx][r];
    }
}

// ---------------------------------------------------------------------------
// generic bf16 transpose with strides: in [R][C] (ldi) -> out [C][R] (ldo)
// ---------------------------------------------------------------------------
__global__ void transpose_bf16_kernel(const bf16_t* __restrict__ in,
                                      bf16_t* __restrict__ out,
                                      int ldi, int ldo) {
    __shared__ float tile[32][33];
    int bx = blockIdx.x * 32;  // C offset
    int by = blockIdx.y * 32;  // R offset
    int tx = threadIdx.x, ty = threadIdx.y;
#pragma unroll
    for (int i = 0; i < 4; i++) {
        int r = ty + i * 8;
        tile[r][tx] = (float)in[(size_t)(by + r) * ldi + bx + tx];
    }
    __syncthreads();
#pragma unroll
    for (int i = 0; i < 4; i++) {
        int r = ty + i * 8;
        out[(size_t)(bx + r) * ldo + by + tx] = (bf16_t)tile[tx][r];
    }
}

// ---------------------------------------------------------------------------
// bf16 GEMM (m97 structure): C[M][N] = A[M][K] @ BT[N][K]^T
// 128x128 tile, BK=32, 4 waves, global_load_lds width-16 staging (no pad).
// ---------------------------------------------------------------------------
template <typename OutT>
__global__ __launch_bounds__(256) void gemm_bt_kernel(
        const bf16_t* __restrict__ A, const bf16_t* __restrict__ BT,
        OutT* __restrict__ C, int M, int N, int K) {
    constexpr int BM = 128, BN = 128, BK = 32;
    __shared__ bf16_t As[BM * BK];
    __shared__ bf16_t Bs[BN * BK];

    const int tid  = threadIdx.x;
    const int lane = tid & 63;
    const int wave = tid >> 6;
    const int wm = (wave >> 1) * 64;
    const int wn = (wave & 1) * 64;
    const int quad = lane >> 4;
    const int l16  = lane & 15;
    const int m0 = blockIdx.y * BM;
    const int n0 = blockIdx.x * BN;

    const int sr  = tid >> 2;        // 0..63
    const int sc8 = (tid & 3) * 8;   // 0,8,16,24
    const bf16_t* Ag = A  + (size_t)(m0 + sr) * K + sc8;
    const bf16_t* Bg = BT + (size_t)(n0 + sr) * K + sc8;
    bf16_t* AsW0 = &As[sr * BK + sc8];
    bf16_t* AsW1 = &As[(sr + 64) * BK + sc8];
    bf16_t* BsW0 = &Bs[sr * BK + sc8];
    bf16_t* BsW1 = &Bs[(sr + 64) * BK + sc8];

    floatx4 acc[4][4] = {};

    for (int k0 = 0; k0 < K; k0 += BK) {
        gload_lds16(Ag + k0, AsW0);
        gload_lds16(Ag + k0 + (size_t)64 * K, AsW1);
        gload_lds16(Bg + k0, BsW0);
        gload_lds16(Bg + k0 + (size_t)64 * K, BsW1);
        asm volatile("s_waitcnt vmcnt(0)" ::: "memory");
        __syncthreads();

        bf16x8 af[4], bfr[4];
#pragma unroll
        for (int mt = 0; mt < 4; mt++)
            af[mt] = *(const bf16x8*)&As[(wm + mt * 16 + l16) * BK + quad * 8];
#pragma unroll
        for (int nt = 0; nt < 4; nt++)
            bfr[nt] = *(const bf16x8*)&Bs[(wn + nt * 16 + l16) * BK + quad * 8];
#pragma unroll
        for (int mt = 0; mt < 4; mt++)
#pragma unroll
            for (int nt = 0; nt < 4; nt++)
                acc[mt][nt] = __builtin_amdgcn_mfma_f32_16x16x32_bf16(
                    af[mt], bfr[nt], acc[mt][nt], 0, 0, 0);
        __syncthreads();
    }

#pragma unroll
    for (int mt = 0; mt < 4; mt++)
#pragma unroll
        for (int nt = 0; nt < 4; nt++)
#pragma unroll
            for (int rg = 0; rg < 4; rg++) {
                int row = m0 + wm + mt * 16 + quad * 4 + rg;
                int col = n0 + wn + nt * 16 + l16;
                C[(size_t)row * N + col] = (OutT)acc[mt][nt][rg];
            }
}

// ---------------------------------------------------------------------------
// Flash attention, causal, RoPE fused.
//  QKV [S][6144] bf16 (cols: Q 0..4095 | K 4096..5119 | V 5120..6143), un-roped
//  Vt  [NKV][HD][S] bf16
//  O   [S][4096] bf16
// 512 thr = 8 waves; BQ=128 (16 rows/wave); K-tiles of 64.
// 1-D grid of 512: h = bid&31, g = bid>>5, qt = g<8 ? g : 23-g (pair-balanced)
// ---------------------------------------------------------------------------
__global__ __launch_bounds__(512) void attn_kernel(
        const bf16_t* __restrict__ QKV, const bf16_t* __restrict__ Vt,
        const float* __restrict__ fcos, const float* __restrict__ fsin,
        bf16_t* __restrict__ O) {
    constexpr int BK = 64;
    constexpr int KS = HD + 8;   // 136 elem stride: 272B, bank-stride 4 -> conflict-free
    constexpr int VS = BK + 8;   // 72  elem stride: 144B
    __shared__ bf16_t Ks[BK][KS];        // 17408 B
    __shared__ bf16_t Vs[HD][VS];        // 18432 B
    __shared__ bf16_t Ps[8][16][72];     // 18432 B  (wave-private rows)

    const int tid  = threadIdx.x;
    const int lane = tid & 63;
    const int wave = tid >> 6;
    const int quad = lane >> 4;
    const int l16  = lane & 15;

    const int bid = blockIdx.x;
    const int h   = bid & 31;
    const int g   = bid >> 5;
    const int qt  = (g < 8) ? g : 23 - g;
    const int q0  = qt * 128;
    const int hkv = h >> 2;

    // ---- Q fragments with in-register RoPE ----
    const int qrow = q0 + wave * 16 + l16;
    bf16x8 qf[4];
    {
        const bf16_t* Qg = QKV + (size_t)qrow * QLD + h * HD;
        const float* cr = fcos + qrow * 64;
        const float* sr = fsin + qrow * 64;
#pragma unroll
        for (int c = 0; c < 4; c++) {
            bf16x8 v = *(const bf16x8*)(Qg + c * 32 + quad * 8);
#pragma unroll
            for (int u = 0; u < 4; u++) {
                int fi = c * 16 + quad * 4 + u;
                float cc = cr[fi], ss = sr[fi];
                float re = (float)v[2 * u], im = (float)v[2 * u + 1];
                v[2 * u]     = (bf16_t)(re * cc - im * ss);
                v[2 * u + 1] = (bf16_t)(re * ss + im * cc);
            }
            qf[c] = v;
        }
    }

    floatx4 o_acc[8] = {};
    float m_run[4], l_run[4];
#pragma unroll
    for (int i = 0; i < 4; i++) { m_run[i] = -1e30f; l_run[i] = 0.f; }
    const float scale = 0.08838834764831845f;  // 1/sqrt(128)

    const int q_lo = q0 + wave * 16;
    const int q_hi = q_lo + 15;
    const int ntiles = q0 / BK + 2;

    // staging index precompute
    const int krr = tid >> 4;           // 0..31
    const int kcc = (tid & 15) * 8;     // 0..120
    const int vr  = tid >> 3;           // 0..63
    const int vc  = (tid & 7) * 8;      // 0..56
    const bf16_t* Vg = Vt + (size_t)hkv * HD * S_LEN;

    for (int t = 0; t < ntiles; t++) {
        const int k0 = t * BK;

        // ---- stage K tile (with fused RoPE) + V^T tile ----
#pragma unroll
        for (int p = 0; p < 2; p++) {
            int krow = k0 + p * 32 + krr;
            bf16x8 v = *(const bf16x8*)(QKV + (size_t)krow * QLD + DIM_ + hkv * HD + kcc);
            const float* cr = fcos + krow * 64;
            const float* sr = fsin + krow * 64;
#pragma unroll
            for (int u = 0; u < 4; u++) {
                int fi = kcc / 2 + u;
                float cc = cr[fi], ss = sr[fi];
                float re = (float)v[2 * u], im = (float)v[2 * u + 1];
                v[2 * u]     = (bf16_t)(re * cc - im * ss);
                v[2 * u + 1] = (bf16_t)(re * ss + im * cc);
            }
            *(bf16x8*)&Ks[p * 32 + krr][kcc] = v;
        }
#pragma unroll
        for (int p = 0; p < 2; p++)
            *(bf16x8*)&Vs[p * 64 + vr][vc] =
                *(const bf16x8*)(Vg + (size_t)(p * 64 + vr) * S_LEN + k0 + vc);
        __syncthreads();

        if (k0 <= q_hi) {  // tile not fully masked for this wave
            // ---- S = Q K^T (16 x 64) ----
            floatx4 sc4[4] = {};
#pragma unroll
            for (int nt = 0; nt < 4; nt++)
#pragma unroll
                for (int ks = 0; ks < 4; ks++) {
                    bf16x8 kf = *(const bf16x8*)&Ks[nt * 16 + l16][ks * 32 + quad * 8];
                    sc4[nt] = __builtin_amdgcn_mfma_f32_16x16x32_bf16(qf[ks], kf, sc4[nt], 0, 0, 0);
                }

            const bool needmask = (k0 + BK - 1) > q_lo;
#pragma unroll
            for (int nt = 0; nt < 4; nt++)
#pragma unroll
                for (int rg = 0; rg < 4; rg++) {
                    float s = sc4[nt][rg] * scale;
                    if (needmask) {
                        int qg = q_lo + quad * 4 + rg;
                        int kg = k0 + nt * 16 + l16;
                        if (kg > qg) s = -1e30f;
                    }
                    sc4[nt][rg] = s;
                }

            // ---- online softmax (rows = quad*4+rg, cols across l16 x nt) ----
            float alpha[4];
#pragma unroll
            for (int rg = 0; rg < 4; rg++) {
                float m = fmaxf(fmaxf(sc4[0][rg], sc4[1][rg]), fmaxf(sc4[2][rg], sc4[3][rg]));
#pragma unroll
                for (int off = 8; off >= 1; off >>= 1)
                    m = fmaxf(m, __shfl_xor(m, off, 64));
                float mn = fmaxf(m_run[rg], m);
                alpha[rg] = __expf(m_run[rg] - mn);
                m_run[rg] = mn;
            }
            float rsum[4] = {0.f, 0.f, 0.f, 0.f};
#pragma unroll
            for (int nt = 0; nt < 4; nt++)
#pragma unroll
                for (int rg = 0; rg < 4; rg++) {
                    float p = __expf(sc4[nt][rg] - m_run[rg]);
                    sc4[nt][rg] = p;
                    rsum[rg] += p;
                }
#pragma unroll
            for (int rg = 0; rg < 4; rg++) {
                float s = rsum[rg];
#pragma unroll
                for (int off = 8; off >= 1; off >>= 1)
                    s += __shfl_xor(s, off, 64);
                l_run[rg] = l_run[rg] * alpha[rg] + s;
            }
#pragma unroll
            for (int dt = 0; dt < 8; dt++)
#pragma unroll
                for (int rg = 0; rg < 4; rg++) o_acc[dt][rg] *= alpha[rg];

            // ---- P: C-layout -> LDS -> A-layout (wave-private, no barrier) ----
#pragma unroll
            for (int nt = 0; nt < 4; nt++)
#pragma unroll
                for (int rg = 0; rg < 4; rg++)
                    Ps[wave][quad * 4 + rg][nt * 16 + l16] = (bf16_t)sc4[nt][rg];
            asm volatile("s_waitcnt lgkmcnt(0)" ::: "memory");

            // ---- O += P V ----
#pragma unroll
            for (int ks = 0; ks < 2; ks++) {
                bf16x8 pf = *(const bf16x8*)&Ps[wave][l16][ks * 32 + quad * 8];
#pragma unroll
                for (int dt = 0; dt < 8; dt++) {
                    bf16x8 vf = *(const bf16x8*)&Vs[dt * 16 + l16][ks * 32 + quad * 8];
                    o_acc[dt] = __builtin_amdgcn_mfma_f32_16x16x32_bf16(pf, vf, o_acc[dt], 0, 0, 0);
                }
            }
        }
        __syncthreads();
    }

    // ---- epilogue ----
#pragma unroll
    for (int rg = 0; rg < 4; rg++) {
        float inv_l = 1.0f / l_run[rg];
#pragma unroll
        for (int dt = 0; dt < 8; dt++) {
            int row = q0 + wave * 16 + quad * 4 + rg;
            int col = h * HD + dt * 16 + l16;
            O[(size_t)row * (NH * HD) + col] = (bf16_t)(o_acc[dt][rg] * inv_l);
        }
    }
}

// ---------------------------------------------------------------------------
// launch
// ---------------------------------------------------------------------------
extern "C" void kernel_launch(void* const* d_in, const int* in_sizes, int n_in,
                              void* d_out, int out_size, void* d_ws, size_t ws_size,
                              hipStream_t stream) {
    const float* x    = (const float*)d_in[0];
    const float* wq   = (const float*)d_in[1];
    const float* wk   = (const float*)d_in[2];
    const float* wv   = (const float*)d_in[3];
    const float* wo   = (const float*)d_in[4];
    const float* fcos = (const float*)d_in[5];
    const float* fsin = (const float*)d_in[6];
    float* out = (float*)d_out;

    char* ws = (char*)d_ws;
    constexpr size_t MB = 1024 * 1024;
    bf16_t* xb    = (bf16_t*)(ws + 0 * MB);     // 16 MB  [2048][4096]
    bf16_t* wqkvT = (bf16_t*)(ws + 16 * MB);    // 48 MB  [6144][4096]
    bf16_t* woT   = (bf16_t*)(ws + 64 * MB);    // 32 MB  [4096][4096]
    bf16_t* QKVb  = (bf16_t*)(ws + 96 * MB);    // 24 MB  [2048][6144]
    bf16_t* Vt    = (bf16_t*)(ws + 120 * MB);   //  4 MB  [8][128][2048]
    bf16_t* attnb = (bf16_t*)(ws + 124 * MB);   // 16 MB  [2048][4096]

    // 1. convert x; transpose-convert all weights (one kernel)
    f32_to_bf16_kernel<<<S_LEN * DIM_ / 8 / 256, 256, 0, stream>>>(x, xb, S_LEN * DIM_);
    transpose_weights_kernel<<<40960, dim3(32, 8), 0, stream>>>(wq, wk, wv, wo, wqkvT, woT);

    // 2. fused QKV projection: [2048][4096] x [6144][4096]^T -> [2048][6144]
    gemm_bt_kernel<bf16_t><<<dim3(QLD / 128, S_LEN / 128), 256, 0, stream>>>(
        xb, wqkvT, QKVb, S_LEN, QLD, DIM_);

    // 3. V^T: QKVb cols 5120..6143 -> Vt [8][128][2048]
    transpose_bf16_kernel<<<dim3(KV_DIM / 32, S_LEN / 32), dim3(32, 8), 0, stream>>>(
        QKVb + 5120, Vt, QLD, S_LEN);

    // 4. causal flash attention (RoPE fused)
    attn_kernel<<<512, 512, 0, stream>>>(QKVb, Vt, fcos, fsin, attnb);

    // 5. output projection (fp32 out)
    gemm_bt_kernel<float><<<dim3(DIM_ / 128, S_LEN / 128), 256, 0, stream>>>(
        attnb, woT, out, S_LEN, DIM_, DIM_);
}